// Round 8
// baseline (67.359 us; speedup 1.0000x reference)
//
#include <hip/hip_runtime.h>
#include <hip/hip_bf16.h>

// RelationalDistMult: B=8, N=1024, DE=128, R=8, DR=64, D=192.
// scores[b,r,n,m] = sum_k w[r,k]*node[b,n,k]*node[b,m,k] + c[b,r]
//   c[b,r] = sum_d w[r,DE+d]*rel[b,r,d]^2
// out = sigmoid(scores) f32 [B,R,N,N] = 256 MB -> HBM-write-bound
// (fill ~7 TB/s => ~38 us floor; rdm7 56.8; rdm10 55.9).
//
// Round 11 = rdm10 + BALANCED GRID. rdm10's grid was 8 x 136 = 1088 blocks
// = 4.25/CU: 64 CUs draw a 5th block -> tail runs at fractional occupancy;
// diagonal tasks also do half the stores of off-diag ones (cost noise).
// Repack: merge the 16 diagonal 64-tiles per b into 8 two-tile tasks.
//   off-diag task: 1 tile, 8 r x (16 MFMA + 8 f32x4 stores + bounce)
//   merged-diag:   2 tiles, each 8 r x (16 MFMA + 4 f32x4 stores)
//   -> store work identical (64 f32x4/wave), MFMA surplus is free
//      (stores are the bottleneck).
// 120 + 8 = 128 tasks x 8 b = 1024 blocks = EXACTLY 4/CU, 3 resident.
// Inner loop, numerics (RNE cvt8), bounce transpose: byte-identical rdm10.

typedef __attribute__((ext_vector_type(8))) short bf16x8;
typedef __attribute__((ext_vector_type(4))) float f32x4;

constexpr int Bc = 8, Nc = 1024, DEc = 128, Rc = 8, DRc = 64, Dc = 192;

static __device__ __forceinline__ float fast_sigmoid(float x) {
    // sigmoid(x) = 1 / (1 + 2^(-x*log2e)); v_exp_f32 computes 2^x.
    float e;
    asm("v_exp_f32 %0, %1" : "=v"(e) : "v"(x * -1.44269504f));
    float s;
    asm("v_rcp_f32 %0, %1" : "=v"(s) : "v"(e + 1.0f));
    return s;
}

static __device__ __forceinline__ bf16x8 cvt8(const f32x4 a, const f32x4 b) {
    union { bf16x8 v; unsigned u[4]; } r;
    asm("v_cvt_pk_bf16_f32 %0, %1, %2" : "=v"(r.u[0]) : "v"(a[0]), "v"(a[1]));
    asm("v_cvt_pk_bf16_f32 %0, %1, %2" : "=v"(r.u[1]) : "v"(a[2]), "v"(a[3]));
    asm("v_cvt_pk_bf16_f32 %0, %1, %2" : "=v"(r.u[2]) : "v"(b[0]), "v"(b[1]));
    asm("v_cvt_pk_bf16_f32 %0, %1, %2" : "=v"(r.u[3]) : "v"(b[2]), "v"(b[3]));
    return r.v;
}

__global__ __launch_bounds__(256, 3) void rdm11(
    const float* __restrict__ node,   // [B,N,DE]
    const float* __restrict__ rel,    // [B,R,DR]
    const float* __restrict__ w,      // [R,D]
    float* __restrict__ out)          // [B,R,N,N]
{
    __shared__ float Ns[64 * 132];        // raw n-slab f32, stride 132
    __shared__ float tb[4 * 32 * 37];     // per-wave transpose bounce
    __shared__ float Cs[8];

    const int lin  = blockIdx.x;
    const int b    = lin & 7;             // XCD-major: node[b] L2-resident
    const int task = lin >> 3;            // 0..127

    // task decode: 0..119 = off-diag pairs (i<j over 16 tiles);
    //              120..127 = merged diagonal pair d (tiles 2d, 2d+1).
    int ti0, tj0, nsub;
    if (task < 120) {
        int t = task, ii = 0, base = 0;
        while (t >= base + (15 - ii)) { base += 15 - ii; ++ii; }
        ti0 = ii; tj0 = ii + 1 + (t - base);
        nsub = 1;
    } else {
        ti0 = (task - 120) * 2;           // first diag tile; second = +1
        tj0 = ti0;
        nsub = 2;
    }

    const int tid  = threadIdx.x;
    const int lane = tid & 63;
    const int wid  = tid >> 6;            // 0..3
    const int wm   = (wid >> 1) * 32;     // wave m offset in 64-tile
    const int wn   = (wid & 1) * 32;      // wave n offset in 64-tile
    const int lr   = lane & 15;
    const int lkw  = (lane >> 4) * 8;     // k word offset within 32-k step

    const float* nodeb = node + (long)b * Nc * DEc;

    // --- c[b,0..7]: wave 0, 8 lanes per r, 8 d-elems per lane ---
    if (tid < 64) {
        const int r8 = lane >> 3;
        const int d0 = (lane & 7) * 8;
        const float* wp = w + r8 * Dc + DEc + d0;
        const float* rp = rel + ((long)b * Rc + r8) * DRc + d0;
        float cv = 0.f;
        #pragma unroll
        for (int q = 0; q < 8; ++q) { const float rv = rp[q]; cv += wp[q] * rv * rv; }
        cv += __shfl_xor(cv, 1, 64);
        cv += __shfl_xor(cv, 2, 64);
        cv += __shfl_xor(cv, 4, 64);
        if ((lane & 7) == 0) Cs[r8] = cv;
    }

    float* tbw = tb + wid * (32 * 37);

    #pragma unroll 1
    for (int s = 0; s < nsub; ++s) {
        const int i  = ti0 + s;           // n-tile
        const int j  = (nsub == 2) ? i : tj0;  // m-tile
        const int n0 = i * 64;
        const int m0 = j * 64;
        const bool offd = (i != j);

        if (s) __syncthreads();           // all waves done reading prev Ns

        // --- m-side A-fragments: global->reg, bf16 once, reused all 8 r ---
        bf16x8 afr[2][4];                 // [mi][kk]
        #pragma unroll
        for (int mi = 0; mi < 2; ++mi) {
            const float* mp = nodeb + (long)(m0 + wm + mi * 16 + lr) * DEc;
            #pragma unroll
            for (int kk = 0; kk < 4; ++kk) {
                const f32x4 a0 = *(const f32x4*)(mp + kk * 32 + lkw);
                const f32x4 a1 = *(const f32x4*)(mp + kk * 32 + lkw + 4);
                afr[mi][kk] = cvt8(a0, a1);
            }
        }

        // --- stage raw n-slab f32 -> LDS (reused all 8 r) ---
        {
            const int col4 = (tid & 31) * 4;  // 0..124
            const int row0 = tid >> 5;        // 0..7
            #pragma unroll
            for (int p = 0; p < 8; ++p) {
                const int row = row0 + p * 8;
                const float4 v = *(const float4*)(nodeb + (long)(n0 + row) * DEc + col4);
                *(float4*)&Ns[row * 132 + col4] = v;
            }
        }
        __syncthreads();                  // Cs + Ns ready

        #pragma unroll 1
        for (int r = 0; r < Rc; ++r) {
            const float c = Cs[r];
            const float* wr = w + r * Dc;

            // n-side B-fragments: LDS raw + in-register rescale (RNE)
            bf16x8 bfr[2][4];             // [ni][kk]
            #pragma unroll
            for (int ni = 0; ni < 2; ++ni) {
                const int rowB = wn + ni * 16 + lr;
                #pragma unroll
                for (int kk = 0; kk < 4; ++kk) {
                    const f32x4 w0 = *(const f32x4*)(wr + kk * 32 + lkw);
                    const f32x4 w1 = *(const f32x4*)(wr + kk * 32 + lkw + 4);
                    const f32x4 x0 = *(const f32x4*)&Ns[rowB * 132 + kk * 32 + lkw];
                    const f32x4 x1 = *(const f32x4*)&Ns[rowB * 132 + kk * 32 + lkw + 4];
                    bfr[ni][kk] = cvt8(x0 * w0, x1 * w1);
                }
            }

            f32x4 acc[2][2] = {};
            #pragma unroll
            for (int kk = 0; kk < 4; ++kk)
                #pragma unroll
                for (int mi = 0; mi < 2; ++mi)
                    #pragma unroll
                    for (int ni = 0; ni < 2; ++ni)
                        acc[mi][ni] = __builtin_amdgcn_mfma_f32_16x16x32_bf16(
                            afr[mi][kk], bfr[ni][kk], acc[mi][ni], 0, 0, 0);

            float* plane = out + ((long)(b * Rc + r) << 20);

            // direct stores (+ bounce write for the transposed copy)
            #pragma unroll
            for (int mi = 0; mi < 2; ++mi) {
                #pragma unroll
                for (int ni = 0; ni < 2; ++ni) {
                    const int nn = n0 + wn + ni * 16 + lr;
                    const int mm = m0 + wm + mi * 16 + (lane >> 4) * 4;
                    f32x4 v;
                    v[0] = fast_sigmoid(acc[mi][ni][0] + c);
                    v[1] = fast_sigmoid(acc[mi][ni][1] + c);
                    v[2] = fast_sigmoid(acc[mi][ni][2] + c);
                    v[3] = fast_sigmoid(acc[mi][ni][3] + c);
                    *(f32x4*)(plane + (long)nn * Nc + mm) = v;
                    if (offd) {
                        const int n_t = ni * 16 + lr;
                        const int m_t = mi * 16 + (lane >> 4) * 4;
                        *(f32x4*)&tbw[n_t * 37 + m_t] = v;
                    }
                }
            }

            // transposed stores: out[m, n] from wave-private bounce
            if (offd) {
                asm volatile("s_waitcnt lgkmcnt(0)" ::: "memory");
                #pragma unroll
                for (int p = 0; p < 4; ++p) {
                    const int m_t = p * 8 + (lane >> 3);   // 0..31
                    const int n_t = (lane & 7) * 4;        // 0..28
                    f32x4 v;
                    v[0] = tbw[(n_t + 0) * 37 + m_t];
                    v[1] = tbw[(n_t + 1) * 37 + m_t];
                    v[2] = tbw[(n_t + 2) * 37 + m_t];
                    v[3] = tbw[(n_t + 3) * 37 + m_t];
                    *(f32x4*)(plane + (long)(m0 + wm + m_t) * Nc + (n0 + wn + n_t)) = v;
                }
            }
        }
    }
}

extern "C" void kernel_launch(void* const* d_in, const int* in_sizes, int n_in,
                              void* d_out, int out_size, void* d_ws, size_t ws_size,
                              hipStream_t stream) {
    const float* node = (const float*)d_in[0];  // [8,1024,128]
    const float* rel  = (const float*)d_in[1];  // [8,8,64]
    const float* w    = (const float*)d_in[2];  // [8,192]
    float* out = (float*)d_out;                 // [8,8,1024,1024]

    rdm11<<<Bc * 128, 256, 0, stream>>>(node, rel, w, out);
}

// Round 9
// 62.314 us; speedup vs baseline: 1.0810x; 1.0810x over previous
//
#include <hip/hip_runtime.h>
#include <hip/hip_bf16.h>

// RelationalDistMult: B=8, N=1024, DE=128, R=8, DR=64, D=192.
// scores[b,r,n,m] = sum_k w[r,k]*node[b,n,k]*node[b,m,k] + c[b,r]
//   c[b,r] = sum_d w[r,DE+d]*rel[b,r,d]^2
// out = sigmoid(scores) f32 [B,R,N,N] = 256 MB -> HBM-write-bound
// (fill ~7 TB/s => ~38 us floor; rdm10 = 55.9 us best).
//
// Round 12 = rdm10 EXACT BASE (r8's merged-diag repack regressed 20% ->
// reverted) + two micro-fixes:
//  1. direct stores routed through the wave-private bounce too: inst shape
//     goes 16 rows x 64 B (16 pages/inst) -> 8 rows x 128 B (8 pages/inst).
//     Bounce read pattern [p*8+(l>>3)]*37+(l&7)*4 is <=2-way bank aliasing
//     (free, m136). Write pattern and transposed read unchanged (verified).
//  2. task order: 120 off-diag pairs first, 16 light diagonal tasks LAST ->
//     the drain tail is made of the shortest blocks.
// Grid stays 8 x 136 (4.25 blk/CU -- measured fine at 55.9; r8 proved the
// "balanced" repack is worse). Inner loop numerics (RNE cvt8) identical.

typedef __attribute__((ext_vector_type(8))) short bf16x8;
typedef __attribute__((ext_vector_type(4))) float f32x4;

constexpr int Bc = 8, Nc = 1024, DEc = 128, Rc = 8, DRc = 64, Dc = 192;

static __device__ __forceinline__ float fast_sigmoid(float x) {
    // sigmoid(x) = 1 / (1 + 2^(-x*log2e)); v_exp_f32 computes 2^x.
    float e;
    asm("v_exp_f32 %0, %1" : "=v"(e) : "v"(x * -1.44269504f));
    float s;
    asm("v_rcp_f32 %0, %1" : "=v"(s) : "v"(e + 1.0f));
    return s;
}

static __device__ __forceinline__ bf16x8 cvt8(const f32x4 a, const f32x4 b) {
    union { bf16x8 v; unsigned u[4]; } r;
    asm("v_cvt_pk_bf16_f32 %0, %1, %2" : "=v"(r.u[0]) : "v"(a[0]), "v"(a[1]));
    asm("v_cvt_pk_bf16_f32 %0, %1, %2" : "=v"(r.u[1]) : "v"(a[2]), "v"(a[3]));
    asm("v_cvt_pk_bf16_f32 %0, %1, %2" : "=v"(r.u[2]) : "v"(b[0]), "v"(b[1]));
    asm("v_cvt_pk_bf16_f32 %0, %1, %2" : "=v"(r.u[3]) : "v"(b[2]), "v"(b[3]));
    return r.v;
}

__global__ __launch_bounds__(256, 3) void rdm12(
    const float* __restrict__ node,   // [B,N,DE]
    const float* __restrict__ rel,    // [B,R,DR]
    const float* __restrict__ w,      // [R,D]
    float* __restrict__ out)          // [B,R,N,N]
{
    __shared__ float Ns[64 * 132];        // raw n-slab f32, stride 132
    __shared__ float tb[4 * 32 * 37];     // per-wave store bounce
    __shared__ float Cs[8];

    const int lin = blockIdx.x;
    const int b   = lin & 7;              // XCD-major: node[b] L2-resident
    const int tp  = lin >> 3;             // 0..135

    // task decode: 0..119 = off-diag (i<j over 16 tiles), i-major;
    //              120..135 = diagonal tile (i==j) -- light tasks, LAST.
    int i, j;
    if (tp < 120) {
        int t = tp, ii = 0, base = 0;
        while (t >= base + (15 - ii)) { base += 15 - ii; ++ii; }
        i = ii; j = ii + 1 + (t - base);
    } else {
        i = tp - 120; j = i;
    }
    const int n0 = i * 64;
    const int m0 = j * 64;
    const bool offd = (i != j);

    const int tid  = threadIdx.x;
    const int lane = tid & 63;
    const int wid  = tid >> 6;            // 0..3
    const int wm   = (wid >> 1) * 32;     // wave m offset in 64-tile
    const int wn   = (wid & 1) * 32;      // wave n offset in 64-tile
    const int lr   = lane & 15;
    const int lkw  = (lane >> 4) * 8;     // k word offset within 32-k step

    const float* nodeb = node + (long)b * Nc * DEc;

    // --- c[b,0..7]: wave 0, 8 lanes per r, 8 d-elems per lane ---
    if (tid < 64) {
        const int r8 = lane >> 3;
        const int d0 = (lane & 7) * 8;
        const float* wp = w + r8 * Dc + DEc + d0;
        const float* rp = rel + ((long)b * Rc + r8) * DRc + d0;
        float cv = 0.f;
        #pragma unroll
        for (int q = 0; q < 8; ++q) { const float rv = rp[q]; cv += wp[q] * rv * rv; }
        cv += __shfl_xor(cv, 1, 64);
        cv += __shfl_xor(cv, 2, 64);
        cv += __shfl_xor(cv, 4, 64);
        if ((lane & 7) == 0) Cs[r8] = cv;
    }

    // --- m-side A-fragments: global->reg, bf16 once, reused all 8 r ---
    bf16x8 afr[2][4];                     // [mi][kk]
    #pragma unroll
    for (int mi = 0; mi < 2; ++mi) {
        const float* mp = nodeb + (long)(m0 + wm + mi * 16 + lr) * DEc;
        #pragma unroll
        for (int kk = 0; kk < 4; ++kk) {
            const f32x4 a0 = *(const f32x4*)(mp + kk * 32 + lkw);
            const f32x4 a1 = *(const f32x4*)(mp + kk * 32 + lkw + 4);
            afr[mi][kk] = cvt8(a0, a1);
        }
    }

    // --- stage raw n-slab f32 -> LDS (once; reused all 8 r) ---
    {
        const int col4 = (tid & 31) * 4;  // 0..124
        const int row0 = tid >> 5;        // 0..7
        #pragma unroll
        for (int p = 0; p < 8; ++p) {
            const int row = row0 + p * 8;
            const float4 v = *(const float4*)(nodeb + (long)(n0 + row) * DEc + col4);
            *(float4*)&Ns[row * 132 + col4] = v;
        }
    }
    __syncthreads();                      // Cs + Ns ready; last barrier.

    float* tbw = tb + wid * (32 * 37);

    #pragma unroll 1
    for (int r = 0; r < Rc; ++r) {
        const float c = Cs[r];
        const float* wr = w + r * Dc;

        // n-side B-fragments: LDS raw + in-register rescale (RNE)
        bf16x8 bfr[2][4];                 // [ni][kk]
        #pragma unroll
        for (int ni = 0; ni < 2; ++ni) {
            const int rowB = wn + ni * 16 + lr;
            #pragma unroll
            for (int kk = 0; kk < 4; ++kk) {
                const f32x4 w0 = *(const f32x4*)(wr + kk * 32 + lkw);
                const f32x4 w1 = *(const f32x4*)(wr + kk * 32 + lkw + 4);
                const f32x4 x0 = *(const f32x4*)&Ns[rowB * 132 + kk * 32 + lkw];
                const f32x4 x1 = *(const f32x4*)&Ns[rowB * 132 + kk * 32 + lkw + 4];
                bfr[ni][kk] = cvt8(x0 * w0, x1 * w1);
            }
        }

        f32x4 acc[2][2] = {};
        #pragma unroll
        for (int kk = 0; kk < 4; ++kk)
            #pragma unroll
            for (int mi = 0; mi < 2; ++mi)
                #pragma unroll
                for (int ni = 0; ni < 2; ++ni)
                    acc[mi][ni] = __builtin_amdgcn_mfma_f32_16x16x32_bf16(
                        afr[mi][kk], bfr[ni][kk], acc[mi][ni], 0, 0, 0);

        float* plane = out + ((long)(b * Rc + r) << 20);

        // sigmoid -> bounce (always; both store directions read from it)
        #pragma unroll
        for (int mi = 0; mi < 2; ++mi) {
            #pragma unroll
            for (int ni = 0; ni < 2; ++ni) {
                const int n_t = ni * 16 + lr;
                const int m_t = mi * 16 + (lane >> 4) * 4;
                f32x4 v;
                v[0] = fast_sigmoid(acc[mi][ni][0] + c);
                v[1] = fast_sigmoid(acc[mi][ni][1] + c);
                v[2] = fast_sigmoid(acc[mi][ni][2] + c);
                v[3] = fast_sigmoid(acc[mi][ni][3] + c);
                *(f32x4*)&tbw[n_t * 37 + m_t] = v;
            }
        }
        asm volatile("s_waitcnt lgkmcnt(0)" ::: "memory");

        // direct stores from bounce: inst p = 8 n-rows x 128 B (8 pages)
        {
            #pragma unroll
            for (int p = 0; p < 4; ++p) {
                const int n_t = p * 8 + (lane >> 3);   // 0..31
                const int m_t = (lane & 7) * 4;        // 0..28
                const f32x4 v = *(const f32x4*)&tbw[n_t * 37 + m_t];
                *(f32x4*)(plane + (long)(n0 + wn + n_t) * Nc + (m0 + wm + m_t)) = v;
            }
        }

        // transposed stores (off-diag): inst p = 8 m-rows x 128 B
        if (offd) {
            #pragma unroll
            for (int p = 0; p < 4; ++p) {
                const int m_t = p * 8 + (lane >> 3);   // 0..31
                const int n_t = (lane & 7) * 4;        // 0..28
                f32x4 v;
                v[0] = tbw[(n_t + 0) * 37 + m_t];
                v[1] = tbw[(n_t + 1) * 37 + m_t];
                v[2] = tbw[(n_t + 2) * 37 + m_t];
                v[3] = tbw[(n_t + 3) * 37 + m_t];
                *(f32x4*)(plane + (long)(m0 + wm + m_t) * Nc + (n0 + wn + n_t)) = v;
            }
        }
    }
}

extern "C" void kernel_launch(void* const* d_in, const int* in_sizes, int n_in,
                              void* d_out, int out_size, void* d_ws, size_t ws_size,
                              hipStream_t stream) {
    const float* node = (const float*)d_in[0];  // [8,1024,128]
    const float* rel  = (const float*)d_in[1];  // [8,8,64]
    const float* w    = (const float*)d_in[2];  // [8,192]
    float* out = (float*)d_out;                 // [8,8,1024,1024]

    rdm12<<<Bc * 136, 256, 0, stream>>>(node, rel, w, out);
}

// Round 10
// 56.094 us; speedup vs baseline: 1.2008x; 1.1109x over previous
//
#include <hip/hip_runtime.h>
#include <hip/hip_bf16.h>

// RelationalDistMult: B=8, N=1024, DE=128, R=8, DR=64, D=192.
// scores[b,r,n,m] = sum_k w[r,k]*node[b,n,k]*node[b,m,k] + c[b,r]
//   c[b,r] = sum_d w[r,DE+d]*rel[b,r,d]^2
// out = sigmoid(scores) f32 [B,R,N,N] = 256 MB -> HBM-write-bound
// (fill ~7 TB/s => ~38 us floor; rdm10 = 55.9 us best).
//
// Round 13 = rdm10 EXACT REVERT (r8 repack −20%, r9 bounce-direct −10% both
// refuted; acc-direct stores + bounce-transposed is the verified optimum)
// + one isolated micro-opt: sigmoid(x+c) folded to
//   1/(1 + exp2( fma(x, -log2e, cL) )),  cL = c * -log2e  (hoisted per r)
// -> saves 1 VALU/element in the hottest loop. <=1 ulp f32 reorder.
//
// Standing evidence for this structure:
//  - symmetry (r4, +11%) and all-r staging reuse (r2/r7) verified
//  - stores from acc regs overlap bounce writes; only transposed stores
//    wait on LDS (r9 proved serializing direct stores behind lgkm costs 10%)
//  - 8x136 grid, i-major order, 4.25 blk/CU measured better than any repack
//  - zero barriers in the r-loop; 12 waves/CU stream stores continuously

typedef __attribute__((ext_vector_type(8))) short bf16x8;
typedef __attribute__((ext_vector_type(4))) float f32x4;

constexpr int Bc = 8, Nc = 1024, DEc = 128, Rc = 8, DRc = 64, Dc = 192;

static __device__ __forceinline__ float fast_sigmoid2(float x, float cL) {
    // sigmoid(x + c) = 1 / (1 + 2^(-(x+c)*log2e)); cL = c * -log2e.
    const float t = __builtin_fmaf(x, -1.44269504f, cL);
    float e;
    asm("v_exp_f32 %0, %1" : "=v"(e) : "v"(t));
    float s;
    asm("v_rcp_f32 %0, %1" : "=v"(s) : "v"(e + 1.0f));
    return s;
}

static __device__ __forceinline__ bf16x8 cvt8(const f32x4 a, const f32x4 b) {
    union { bf16x8 v; unsigned u[4]; } r;
    asm("v_cvt_pk_bf16_f32 %0, %1, %2" : "=v"(r.u[0]) : "v"(a[0]), "v"(a[1]));
    asm("v_cvt_pk_bf16_f32 %0, %1, %2" : "=v"(r.u[1]) : "v"(a[2]), "v"(a[3]));
    asm("v_cvt_pk_bf16_f32 %0, %1, %2" : "=v"(r.u[2]) : "v"(b[0]), "v"(b[1]));
    asm("v_cvt_pk_bf16_f32 %0, %1, %2" : "=v"(r.u[3]) : "v"(b[2]), "v"(b[3]));
    return r.v;
}

__global__ __launch_bounds__(256, 3) void rdm13(
    const float* __restrict__ node,   // [B,N,DE]
    const float* __restrict__ rel,    // [B,R,DR]
    const float* __restrict__ w,      // [R,D]
    float* __restrict__ out)          // [B,R,N,N]
{
    __shared__ float Ns[64 * 132];        // raw n-slab f32, stride 132
    __shared__ float tb[4 * 32 * 37];     // per-wave transpose bounce
    __shared__ float Cs[8];

    const int lin = blockIdx.x;
    const int b   = lin & 7;              // XCD-major: node[b] L2-resident
    int tp = lin >> 3;                    // 0..135 upper-tri pair over 16 tiles

    int i = 0, base = 0;
    while (tp >= base + (16 - i)) { base += 16 - i; ++i; }
    const int j = i + (tp - base);
    const int n0 = i * 64;
    const int m0 = j * 64;
    const bool offd = (i != j);

    const int tid  = threadIdx.x;
    const int lane = tid & 63;
    const int wid  = tid >> 6;            // 0..3
    const int wm   = (wid >> 1) * 32;     // wave m offset in 64-tile
    const int wn   = (wid & 1) * 32;      // wave n offset in 64-tile
    const int lr   = lane & 15;
    const int lkw  = (lane >> 4) * 8;     // k word offset within 32-k step

    const float* nodeb = node + (long)b * Nc * DEc;

    // --- c[b,0..7]: wave 0, 8 lanes per r, 8 d-elems per lane ---
    if (tid < 64) {
        const int r8 = lane >> 3;
        const int d0 = (lane & 7) * 8;
        const float* wp = w + r8 * Dc + DEc + d0;
        const float* rp = rel + ((long)b * Rc + r8) * DRc + d0;
        float cv = 0.f;
        #pragma unroll
        for (int q = 0; q < 8; ++q) { const float rv = rp[q]; cv += wp[q] * rv * rv; }
        cv += __shfl_xor(cv, 1, 64);
        cv += __shfl_xor(cv, 2, 64);
        cv += __shfl_xor(cv, 4, 64);
        if ((lane & 7) == 0) Cs[r8] = cv;
    }

    // --- m-side A-fragments: global->reg, bf16 once, reused all 8 r ---
    bf16x8 afr[2][4];                     // [mi][kk]
    #pragma unroll
    for (int mi = 0; mi < 2; ++mi) {
        const float* mp = nodeb + (long)(m0 + wm + mi * 16 + lr) * DEc;
        #pragma unroll
        for (int kk = 0; kk < 4; ++kk) {
            const f32x4 a0 = *(const f32x4*)(mp + kk * 32 + lkw);
            const f32x4 a1 = *(const f32x4*)(mp + kk * 32 + lkw + 4);
            afr[mi][kk] = cvt8(a0, a1);
        }
    }

    // --- stage raw n-slab f32 -> LDS (once; reused all 8 r) ---
    {
        const int col4 = (tid & 31) * 4;  // 0..124
        const int row0 = tid >> 5;        // 0..7
        #pragma unroll
        for (int p = 0; p < 8; ++p) {
            const int row = row0 + p * 8;
            const float4 v = *(const float4*)(nodeb + (long)(n0 + row) * DEc + col4);
            *(float4*)&Ns[row * 132 + col4] = v;
        }
    }
    __syncthreads();                      // Cs + Ns ready; last barrier.

    float* tbw = tb + wid * (32 * 37);

    #pragma unroll 1
    for (int r = 0; r < Rc; ++r) {
        const float c  = Cs[r];
        const float cL = c * -1.44269504f;
        const float* wr = w + r * Dc;

        // n-side B-fragments: LDS raw + in-register rescale (RNE)
        bf16x8 bfr[2][4];                 // [ni][kk]
        #pragma unroll
        for (int ni = 0; ni < 2; ++ni) {
            const int rowB = wn + ni * 16 + lr;
            #pragma unroll
            for (int kk = 0; kk < 4; ++kk) {
                const f32x4 w0 = *(const f32x4*)(wr + kk * 32 + lkw);
                const f32x4 w1 = *(const f32x4*)(wr + kk * 32 + lkw + 4);
                const f32x4 x0 = *(const f32x4*)&Ns[rowB * 132 + kk * 32 + lkw];
                const f32x4 x1 = *(const f32x4*)&Ns[rowB * 132 + kk * 32 + lkw + 4];
                bfr[ni][kk] = cvt8(x0 * w0, x1 * w1);
            }
        }

        f32x4 acc[2][2] = {};
        #pragma unroll
        for (int kk = 0; kk < 4; ++kk)
            #pragma unroll
            for (int mi = 0; mi < 2; ++mi)
                #pragma unroll
                for (int ni = 0; ni < 2; ++ni)
                    acc[mi][ni] = __builtin_amdgcn_mfma_f32_16x16x32_bf16(
                        afr[mi][kk], bfr[ni][kk], acc[mi][ni], 0, 0, 0);

        float* plane = out + ((long)(b * Rc + r) << 20);

        // direct stores from acc regs (+ bounce write for the transposed copy)
        #pragma unroll
        for (int mi = 0; mi < 2; ++mi) {
            #pragma unroll
            for (int ni = 0; ni < 2; ++ni) {
                const int nn = n0 + wn + ni * 16 + lr;
                const int mm = m0 + wm + mi * 16 + (lane >> 4) * 4;
                f32x4 v;
                v[0] = fast_sigmoid2(acc[mi][ni][0], cL);
                v[1] = fast_sigmoid2(acc[mi][ni][1], cL);
                v[2] = fast_sigmoid2(acc[mi][ni][2], cL);
                v[3] = fast_sigmoid2(acc[mi][ni][3], cL);
                *(f32x4*)(plane + (long)nn * Nc + mm) = v;
                if (offd) {
                    const int n_t = ni * 16 + lr;
                    const int m_t = mi * 16 + (lane >> 4) * 4;
                    *(f32x4*)&tbw[n_t * 37 + m_t] = v;
                }
            }
        }

        // transposed stores: out[m, n] from wave-private bounce (no barrier)
        if (offd) {
            asm volatile("s_waitcnt lgkmcnt(0)" ::: "memory");
            #pragma unroll
            for (int p = 0; p < 4; ++p) {
                const int m_t = p * 8 + (lane >> 3);   // 0..31
                const int n_t = (lane & 7) * 4;        // 0..28
                f32x4 v;
                v[0] = tbw[(n_t + 0) * 37 + m_t];
                v[1] = tbw[(n_t + 1) * 37 + m_t];
                v[2] = tbw[(n_t + 2) * 37 + m_t];
                v[3] = tbw[(n_t + 3) * 37 + m_t];
                *(f32x4*)(plane + (long)(m0 + wm + m_t) * Nc + (n0 + wn + n_t)) = v;
            }
        }
    }
}

extern "C" void kernel_launch(void* const* d_in, const int* in_sizes, int n_in,
                              void* d_out, int out_size, void* d_ws, size_t ws_size,
                              hipStream_t stream) {
    const float* node = (const float*)d_in[0];  // [8,1024,128]
    const float* rel  = (const float*)d_in[1];  // [8,8,64]
    const float* w    = (const float*)d_in[2];  // [8,192]
    float* out = (float*)d_out;                 // [8,8,1024,1024]

    rdm13<<<Bc * 136, 256, 0, stream>>>(node, rel, w, out);
}